// Round 11
// baseline (365.339 us; speedup 1.0000x reference)
//
#include <hip/hip_runtime.h>
#include <hip/hip_bf16.h>

// Two-layer RGCN (mean aggregation per relation) for MI355X.
// Round 11: round-7 fused structure + column-split blocks for TLP.
//  - occupancy was GRID-limited (782 blocks = 3/CU); col-split -> 1564 blocks
//  - per segment: BUILD (gather) issued BEFORE STAGE so both streams overlap;
//    barrier drain pays max(gather,stage) instead of sum
//  - Bt rows padded to 272B stride (2 lanes/bank; conflict counter is a
//    structural 4/ds_read_b128 floor, layout-independent)
// CSR (node-major), converts unchanged. Best so far: round 7 = 258.8 us.

#define D_IN 128
#define NREL 8
#define BTSTRIDE 136  // ushorts per padded B row (272 B)

typedef short bf16x8 __attribute__((ext_vector_type(8)));
typedef float f32x4 __attribute__((ext_vector_type(4)));

__device__ __forceinline__ ushort cvbf(float f) {  // f32 -> bf16 RNE
    unsigned u = __float_as_uint(f);
    return (ushort)((u + 0x7FFFu + ((u >> 16) & 1u)) >> 16);
}
__device__ __forceinline__ float bflo(unsigned v) { return __uint_as_float(v << 16); }
__device__ __forceinline__ float bfhi(unsigned v) { return __uint_as_float(v & 0xFFFF0000u); }

// ---------------- f32 -> bf16 convert (4 elems/thread) ----------------
__global__ void to_bf16_kernel(const float* __restrict__ in,
                               ushort* __restrict__ out, int n4) {
    int i = blockIdx.x * blockDim.x + threadIdx.x;
    if (i >= n4) return;
    float4 v = ((const float4*)in)[i];
    ushort4 o;
    o.x = cvbf(v.x); o.y = cvbf(v.y); o.z = cvbf(v.z); o.w = cvbf(v.w);
    ((ushort4*)out)[i] = o;
}

// -------- weight pre-transform: bf16 W^T, padded row stride ---------------
// Wt[s][n][k] at ((s*NCOLS + n)*BTSTRIDE + k); k in [0,128). s==NREL: root.
__global__ void wt_transform_kernel(const float* __restrict__ W,
                                    const float* __restrict__ root,
                                    ushort* __restrict__ Wt, int NCOLS) {
    int i = blockIdx.x * blockDim.x + threadIdx.x;
    int tot = (NREL + 1) * D_IN * NCOLS;
    if (i >= tot) return;
    int s = i / (D_IN * NCOLS);
    int r = i - s * D_IN * NCOLS;
    int k = r / NCOLS;
    int n = r - k * NCOLS;
    float v = (s < NREL) ? W[(size_t)s * D_IN * NCOLS + (size_t)k * NCOLS + n]
                         : root[(size_t)k * NCOLS + n];
    Wt[((size_t)s * NCOLS + n) * BTSTRIDE + k] = cvbf(v);
}

// ---------------- CSR build (seg = dst*8 + et, node-major) ----------------
__global__ void count_kernel(const int* __restrict__ dst,
                             const int* __restrict__ et,
                             int* __restrict__ cnt, int E, int N) {
    int e = blockIdx.x * blockDim.x + threadIdx.x;
    if (e < E) atomicAdd(&cnt[dst[e] * NREL + et[e]], 1);
}

__global__ void scan_block_sum(const int* __restrict__ cnt,
                               int* __restrict__ bsum, int nseg) {
    __shared__ int s[256];
    int base = blockIdx.x * 1024 + threadIdx.x * 4;
    int v = 0;
#pragma unroll
    for (int i = 0; i < 4; ++i) {
        int idx = base + i;
        if (idx < nseg) v += cnt[idx];
    }
    s[threadIdx.x] = v;
    __syncthreads();
    for (int off = 128; off > 0; off >>= 1) {
        if (threadIdx.x < off) s[threadIdx.x] += s[threadIdx.x + off];
        __syncthreads();
    }
    if (threadIdx.x == 0) bsum[blockIdx.x] = s[0];
}

__global__ void scan_bsum(int* __restrict__ bsum, int nb) {
    __shared__ int s[512];
    int t = threadIdx.x;
    int my = (t < nb) ? bsum[t] : 0;
    s[t] = my;
    __syncthreads();
    for (int off = 1; off < 512; off <<= 1) {
        int v = (t >= off) ? s[t - off] : 0;
        __syncthreads();
        s[t] += v;
        __syncthreads();
    }
    if (t < nb) bsum[t] = s[t] - my;  // exclusive
}

__global__ void scan_write(const int* __restrict__ cnt,
                           const int* __restrict__ bsum,
                           int* __restrict__ off, int nseg) {
    __shared__ int s[256];
    int t = threadIdx.x;
    int base = blockIdx.x * 1024 + t * 4;
    int v[4];
    int sum = 0;
#pragma unroll
    for (int i = 0; i < 4; ++i) {
        int idx = base + i;
        v[i] = (idx < nseg) ? cnt[idx] : 0;
        sum += v[i];
    }
    s[t] = sum;
    __syncthreads();
    int my = sum;
    for (int o = 1; o < 256; o <<= 1) {
        int x = (t >= o) ? s[t - o] : 0;
        __syncthreads();
        s[t] += x;
        __syncthreads();
    }
    int pre = s[t] - my + bsum[blockIdx.x];
#pragma unroll
    for (int i = 0; i < 4; ++i) {
        int idx = base + i;
        if (idx < nseg) {
            off[idx] = pre;
            pre += v[i];
        }
    }
}

__global__ void bucket_kernel(const int* __restrict__ src,
                              const int* __restrict__ dst,
                              const int* __restrict__ et,
                              int* __restrict__ off,
                              int* __restrict__ sids, int E, int N) {
    int e = blockIdx.x * blockDim.x + threadIdx.x;
    if (e < E) {
        int seg = dst[e] * NREL + et[e];
        int pos = atomicAdd(&off[seg], 1);
        sids[pos] = src[e];
    }
}

// ---------------- fused aggregate + MFMA GEMM ----------------
// out[n][j] = bias[j] + feat[n]@root[:,j]
//           + sum_r mean_{e in seg(n,r)} feat[src_e] @ W[r][:,j]
// Block: 4 waves x 16 nodes, NT 16-col tiles (col block = blockIdx.y).
template <int NCOLS, int NT, bool RELU, bool OUTBF16>
__global__ __launch_bounds__(256) void fused_gemm_kernel(
    const ushort* __restrict__ feat,   // [N][128] bf16
    const int* __restrict__ sids,      // [E] src ids grouped by (dst*8+et)
    const int* __restrict__ endoff,    // [N*8] end offsets
    const ushort* __restrict__ Wt,     // [R+1][NCOLS][BTSTRIDE] bf16 (W^T)
    const float* __restrict__ bias,    // [NCOLS]
    void* __restrict__ outp,           // [N][NCOLS] bf16 or f32
    int N) {
    constexpr int BC = NT * 16;                 // cols per block
    constexpr int SEGU = BC * BTSTRIDE / 8;     // uint4 per staged tile
    __shared__ __align__(16) ushort Bt[BC * BTSTRIDE];

    const int tid = threadIdx.x;
    const int wave = tid >> 6;
    const int lane = tid & 63;
    const int c = lane & 15;   // A-row / D-col within tile
    const int g = lane >> 4;   // k-group
    const int rb = blockIdx.x * 64 + wave * 16;
    const int arow = min(rb + c, N - 1);  // clamped; stores guarded
    const int colbase = blockIdx.y * BC;

    f32x4 acc[NT];
#pragma unroll
    for (int t = 0; t < NT; ++t) acc[t] = (f32x4){0.f, 0.f, 0.f, 0.f};

    const ushort* myrow = feat + (size_t)arow * D_IN + 8 * g;

    bf16x8 aC[4];

#define ACCQ(Q, V)                                        \
    ac[Q][0] += bflo((V).x); ac[Q][1] += bfhi((V).x);     \
    ac[Q][2] += bflo((V).y); ac[Q][3] += bfhi((V).y);     \
    ac[Q][4] += bflo((V).z); ac[Q][5] += bfhi((V).z);     \
    ac[Q][6] += bflo((V).w); ac[Q][7] += bfhi((V).w)

    // gather relation R's segment mean into aC (root: direct row load)
#define BUILD(R)                                                              \
    do {                                                                      \
        if ((R) < NREL) {                                                     \
            int _b = arow * NREL + (R);                                       \
            int _st = (_b == 0) ? 0 : endoff[_b - 1];                         \
            int _en = endoff[_b];                                             \
            int _deg = _en - _st;                                             \
            float ac[4][8];                                                   \
            _Pragma("unroll") for (int q = 0; q < 4; ++q)                     \
                _Pragma("unroll") for (int j = 0; j < 8; ++j) ac[q][j] = 0.f; \
            for (int e = _st; e < _en; ++e) {                                 \
                const ushort* fr = feat + (size_t)sids[e] * D_IN + 8 * g;     \
                uint4 v0 = *(const uint4*)(fr);                               \
                uint4 v1 = *(const uint4*)(fr + 32);                          \
                uint4 v2 = *(const uint4*)(fr + 64);                          \
                uint4 v3 = *(const uint4*)(fr + 96);                          \
                ACCQ(0, v0); ACCQ(1, v1); ACCQ(2, v2); ACCQ(3, v3);           \
            }                                                                 \
            float inv = (_deg > 0) ? 1.0f / (float)_deg : 0.0f;               \
            _Pragma("unroll") for (int q = 0; q < 4; ++q) {                   \
                uint4 pk;                                                     \
                pk.x = (unsigned)cvbf(ac[q][0] * inv) |                       \
                       ((unsigned)cvbf(ac[q][1] * inv) << 16);                \
                pk.y = (unsigned)cvbf(ac[q][2] * inv) |                       \
                       ((unsigned)cvbf(ac[q][3] * inv) << 16);                \
                pk.z = (unsigned)cvbf(ac[q][4] * inv) |                       \
                       ((unsigned)cvbf(ac[q][5] * inv) << 16);                \
                pk.w = (unsigned)cvbf(ac[q][6] * inv) |                       \
                       ((unsigned)cvbf(ac[q][7] * inv) << 16);                \
                aC[q] = *(bf16x8*)&pk;                                        \
            }                                                                 \
        } else {                                                              \
            _Pragma("unroll") for (int q = 0; q < 4; ++q)                     \
                aC[q] = *(const bf16x8*)(myrow + 32 * q);                     \
        }                                                                     \
    } while (0)

#define STAGE(S)                                                              \
    do {                                                                      \
        const uint4* srcw = (const uint4*)(Wt + ((size_t)(S)*NCOLS + colbase) * BTSTRIDE); \
        uint4* dstw = (uint4*)Bt;                                             \
        _Pragma("unroll") for (int i = 0; i < SEGU / 256; ++i)                \
            dstw[tid + i * 256] = srcw[tid + i * 256];                        \
        if (SEGU % 256) {                                                     \
            int i = (SEGU / 256) * 256 + tid;                                 \
            if (i < SEGU) dstw[i] = srcw[i];                                  \
        }                                                                     \
    } while (0)

    for (int s = 0; s <= NREL; ++s) {
        BUILD(s);   // gather loads issue first
        STAGE(s);   // weight tile loads overlap gather; both drain at barrier
        __syncthreads();
#pragma unroll
        for (int q = 0; q < 4; ++q) {
#pragma unroll
            for (int t = 0; t < NT; ++t) {
                const ushort* bp = Bt + (t * 16 + c) * BTSTRIDE + q * 32 + 8 * g;
                bf16x8 b = *(const bf16x8*)bp;
                acc[t] = __builtin_amdgcn_mfma_f32_16x16x32_bf16(aC[q], b, acc[t], 0, 0, 0);
            }
        }
        __syncthreads();  // Bt consumption complete before next STAGE
    }

    // epilogue: D layout col=lane&15, row=(lane>>4)*4+reg
#pragma unroll
    for (int t = 0; t < NT; ++t) {
        float bv = bias[colbase + t * 16 + c];
#pragma unroll
        for (int r = 0; r < 4; ++r) {
            int orow = rb + 4 * g + r;
            if (orow < N) {
                float v = acc[t][r] + bv;
                if (RELU) v = fmaxf(v, 0.0f);
                if (OUTBF16)
                    ((ushort*)outp)[(size_t)orow * NCOLS + colbase + t * 16 + c] = cvbf(v);
                else
                    ((float*)outp)[(size_t)orow * NCOLS + colbase + t * 16 + c] = v;
            }
        }
    }
#undef BUILD
#undef STAGE
#undef ACCQ
}

extern "C" void kernel_launch(void* const* d_in, const int* in_sizes, int n_in,
                              void* d_out, int out_size, void* d_ws, size_t ws_size,
                              hipStream_t stream) {
    const float* x = (const float*)d_in[0];
    const int* ei = (const int*)d_in[1];
    const int* et = (const int*)d_in[2];
    const float* W1 = (const float*)d_in[3];
    const float* root1 = (const float*)d_in[4];
    const float* bias1 = (const float*)d_in[5];
    const float* W2 = (const float*)d_in[6];
    const float* root2 = (const float*)d_in[7];
    const float* bias2 = (const float*)d_in[8];
    float* out = (float*)d_out;

    const int N = in_sizes[0] / D_IN;  // 50000
    const int E = in_sizes[2];         // 800000
    const int* src = ei;
    const int* dst = ei + E;
    const int NSEG = NREL * N;            // 400000
    const int NB = (NSEG + 1023) / 1024;  // 391 (<=512 for scan_bsum)

    // workspace layout (all 16B-aligned)
    ushort* xb = (ushort*)d_ws;                      // N*128 bf16 = 12.8 MB
    ushort* hb = xb + (size_t)N * D_IN;              // N*128 bf16 = 12.8 MB
    ushort* wt1 = hb + (size_t)N * D_IN;             // 9*128*136 bf16
    ushort* wt2 = wt1 + (size_t)(NREL + 1) * D_IN * BTSTRIDE;  // 9*64*136
    int* off = (int*)(wt2 + (size_t)(NREL + 1) * 64 * BTSTRIDE);  // NSEG ints
    int* sids = off + NSEG;                          // E ints
    int* cnt = sids + E;                             // NSEG ints
    int* bsum = cnt + NSEG;                          // NB ints

    // ---- input conversions / weight transforms (independent) ----
    to_bf16_kernel<<<(N * D_IN / 4 + 255) / 256, 256, 0, stream>>>(x, xb, N * D_IN / 4);
    wt_transform_kernel<<<((NREL + 1) * D_IN * 128 + 255) / 256, 256, 0, stream>>>(
        W1, root1, wt1, 128);
    wt_transform_kernel<<<((NREL + 1) * D_IN * 64 + 255) / 256, 256, 0, stream>>>(
        W2, root2, wt2, 64);

    // ---- CSR build (edge set identical for both layers) ----
    hipMemsetAsync(cnt, 0, (size_t)NSEG * sizeof(int), stream);
    count_kernel<<<(E + 255) / 256, 256, 0, stream>>>(dst, et, cnt, E, N);
    scan_block_sum<<<NB, 256, 0, stream>>>(cnt, bsum, NSEG);
    scan_bsum<<<1, 512, 0, stream>>>(bsum, NB);
    scan_write<<<NB, 256, 0, stream>>>(cnt, bsum, off, NSEG);
    bucket_kernel<<<(E + 255) / 256, 256, 0, stream>>>(src, dst, et, off, sids, E, N);
    // off[] now holds END offsets per segment.

    const int rowBlocks = (N + 63) / 64;  // 782

    // ---- layer 1: 128 cols = 2 col-blocks of NT=4 ----
    fused_gemm_kernel<128, 4, true, true><<<dim3(rowBlocks, 2), 256, 0, stream>>>(
        xb, sids, off, wt1, bias1, hb, N);

    // ---- layer 2: 64 cols = 2 col-blocks of NT=2 ----
    fused_gemm_kernel<64, 2, false, false><<<dim3(rowBlocks, 2), 256, 0, stream>>>(
        hb, sids, off, wt2, bias2, out, N);
}

// Round 12
// 276.258 us; speedup vs baseline: 1.3225x; 1.3225x over previous
//
#include <hip/hip_runtime.h>
#include <hip/hip_bf16.h>

// Two-layer RGCN (mean aggregation per relation) for MI355X.
// Round 12: revert to round-6 pipeline (262.4 us; separate agg + MFMA GEMM —
// measured better than all fused variants of rounds 7-11, which were
// latency-bound at 26-31% occupancy). One change: leaner aggregate_kernel
// (no shfl broadcast; direct uniform sids load per edge; 16-lane group per
// segment, uint4 row slices). CSR relation-major (seg = et*N+dst) as in r6.

#define D_IN 128
#define NREL 8

typedef short bf16x8 __attribute__((ext_vector_type(8)));
typedef float f32x4 __attribute__((ext_vector_type(4)));

__device__ __forceinline__ ushort cvbf(float f) {  // f32 -> bf16 RNE
    unsigned u = __float_as_uint(f);
    return (ushort)((u + 0x7FFFu + ((u >> 16) & 1u)) >> 16);
}
__device__ __forceinline__ float bflo(unsigned v) { return __uint_as_float(v << 16); }
__device__ __forceinline__ float bfhi(unsigned v) { return __uint_as_float(v & 0xFFFF0000u); }

// ---------------- f32 -> bf16 convert (4 elems/thread) ----------------
__global__ void to_bf16_kernel(const float* __restrict__ in,
                               ushort* __restrict__ out, int n4) {
    int i = blockIdx.x * blockDim.x + threadIdx.x;
    if (i >= n4) return;
    float4 v = ((const float4*)in)[i];
    ushort4 o;
    o.x = cvbf(v.x); o.y = cvbf(v.y); o.z = cvbf(v.z); o.w = cvbf(v.w);
    ((ushort4*)out)[i] = o;
}

// ---------------- weight pre-transform: bf16, transposed, XOR-swizzled ------
// Wt[s][n][k'] where byte-in-row = (k*2) ^ ((n&7)<<4). Segment s<NREL from W,
// s==NREL from root.
__global__ void wt_transform_kernel(const float* __restrict__ W,
                                    const float* __restrict__ root,
                                    ushort* __restrict__ Wt, int NCOLS) {
    int i = blockIdx.x * blockDim.x + threadIdx.x;
    int tot = (NREL + 1) * D_IN * NCOLS;
    if (i >= tot) return;
    int s = i / (D_IN * NCOLS);
    int r = i - s * D_IN * NCOLS;
    int k = r / NCOLS;
    int n = r - k * NCOLS;
    float v = (s < NREL) ? W[(size_t)s * D_IN * NCOLS + (size_t)k * NCOLS + n]
                         : root[(size_t)k * NCOLS + n];
    int byteoff = (k << 1) ^ ((n & 7) << 4);
    Wt[(size_t)s * NCOLS * D_IN + (size_t)n * D_IN + (byteoff >> 1)] = cvbf(v);
}

// ---------------- CSR build (seg = et*N + dst, relation-major) -------------
__global__ void count_kernel(const int* __restrict__ dst,
                             const int* __restrict__ et,
                             int* __restrict__ cnt, int E, int N) {
    int e = blockIdx.x * blockDim.x + threadIdx.x;
    if (e < E) atomicAdd(&cnt[et[e] * N + dst[e]], 1);
}

__global__ void scan_block_sum(const int* __restrict__ cnt,
                               int* __restrict__ bsum, int nseg) {
    __shared__ int s[256];
    int base = blockIdx.x * 1024 + threadIdx.x * 4;
    int v = 0;
#pragma unroll
    for (int i = 0; i < 4; ++i) {
        int idx = base + i;
        if (idx < nseg) v += cnt[idx];
    }
    s[threadIdx.x] = v;
    __syncthreads();
    for (int off = 128; off > 0; off >>= 1) {
        if (threadIdx.x < off) s[threadIdx.x] += s[threadIdx.x + off];
        __syncthreads();
    }
    if (threadIdx.x == 0) bsum[blockIdx.x] = s[0];
}

__global__ void scan_bsum(int* __restrict__ bsum, int nb) {
    __shared__ int s[512];
    int t = threadIdx.x;
    int my = (t < nb) ? bsum[t] : 0;
    s[t] = my;
    __syncthreads();
    for (int off = 1; off < 512; off <<= 1) {
        int v = (t >= off) ? s[t - off] : 0;
        __syncthreads();
        s[t] += v;
        __syncthreads();
    }
    if (t < nb) bsum[t] = s[t] - my;  // exclusive
}

__global__ void scan_write(const int* __restrict__ cnt,
                           const int* __restrict__ bsum,
                           int* __restrict__ off, int nseg) {
    __shared__ int s[256];
    int t = threadIdx.x;
    int base = blockIdx.x * 1024 + t * 4;
    int v[4];
    int sum = 0;
#pragma unroll
    for (int i = 0; i < 4; ++i) {
        int idx = base + i;
        v[i] = (idx < nseg) ? cnt[idx] : 0;
        sum += v[i];
    }
    s[t] = sum;
    __syncthreads();
    int my = sum;
    for (int o = 1; o < 256; o <<= 1) {
        int x = (t >= o) ? s[t - o] : 0;
        __syncthreads();
        s[t] += x;
        __syncthreads();
    }
    int pre = s[t] - my + bsum[blockIdx.x];
#pragma unroll
    for (int i = 0; i < 4; ++i) {
        int idx = base + i;
        if (idx < nseg) {
            off[idx] = pre;
            pre += v[i];
        }
    }
}

__global__ void bucket_kernel(const int* __restrict__ src,
                              const int* __restrict__ dst,
                              const int* __restrict__ et,
                              int* __restrict__ off,
                              int* __restrict__ sids, int E, int N) {
    int e = blockIdx.x * blockDim.x + threadIdx.x;
    if (e < E) {
        int seg = et[e] * N + dst[e];
        int pos = atomicAdd(&off[seg], 1);
        sids[pos] = src[e];
    }
}

// -------- atomic-free segment mean (bf16 in/out): 16-lane group / segment ---
// Lane l handles 16 B (8 bf16 channels) of the 256 B row; sids[e] is uniform
// within the group (L1 broadcast), no shfl. 100K independent waves of TLP.
__global__ __launch_bounds__(256) void aggregate_kernel(
    const ushort* __restrict__ feat,    // [N][128] bf16
    const int* __restrict__ sids,       // [E] src ids grouped by segment
    const int* __restrict__ endoff,     // [nseg] end offsets
    ushort* __restrict__ agg,           // [nseg][128] bf16 means
    int nseg) {
    int gid = blockIdx.x * blockDim.x + threadIdx.x;
    int s = gid >> 4;  // one segment per 16 threads
    int l = gid & 15;  // lane within group
    if (s >= nseg) return;

    int end = endoff[s];
    int start = (s == 0) ? 0 : endoff[s - 1];
    int deg = end - start;

    float a0 = 0.f, a1 = 0.f, a2 = 0.f, a3 = 0.f;
    float a4 = 0.f, a5 = 0.f, a6 = 0.f, a7 = 0.f;
    for (int e = start; e < end; ++e) {
        int id = sids[e];  // group-uniform
        uint4 v = ((const uint4*)(feat + (size_t)id * D_IN))[l];
        a0 += bflo(v.x); a1 += bfhi(v.x);
        a2 += bflo(v.y); a3 += bfhi(v.y);
        a4 += bflo(v.z); a5 += bfhi(v.z);
        a6 += bflo(v.w); a7 += bfhi(v.w);
    }
    float inv = (deg > 0) ? 1.0f / (float)deg : 0.0f;
    uint4 o;
    o.x = (unsigned)cvbf(a0 * inv) | ((unsigned)cvbf(a1 * inv) << 16);
    o.y = (unsigned)cvbf(a2 * inv) | ((unsigned)cvbf(a3 * inv) << 16);
    o.z = (unsigned)cvbf(a4 * inv) | ((unsigned)cvbf(a5 * inv) << 16);
    o.w = (unsigned)cvbf(a6 * inv) | ((unsigned)cvbf(a7 * inv) << 16);
    ((uint4*)(agg + (size_t)s * D_IN))[l] = o;
}

// ---------------- MFMA fused RGCN GEMM (round-6 exact) ----------------
// out[n][j] = bias[j] + feat[n]@root[:,j] + sum_r agg[r*N+n] @ W[r][:,j]
template <int NCOLS, bool RELU, bool OUTBF16>
__global__ __launch_bounds__(256) void mfma_gemm_kernel(
    const ushort* __restrict__ feat,  // [N][128] bf16
    const ushort* __restrict__ agg,   // [R][N][128] bf16
    const ushort* __restrict__ Wt,    // [R+1][NCOLS][128] bf16 swizzled
    const float* __restrict__ bias,   // [NCOLS]
    void* __restrict__ outp,          // [N][NCOLS] bf16 or f32
    int N) {
    constexpr int NT = NCOLS / 16;  // 16x16 col-tiles per wave
    __shared__ ushort Bt[NCOLS * D_IN];

    const int tid = threadIdx.x;
    const int wave = tid >> 6;
    const int lane = tid & 63;
    const int c = lane & 15;   // A-row / D-col / B-col within tile
    const int g = lane >> 4;   // k-group
    const int rb = blockIdx.x * 64 + wave * 16;
    const int arow = min(rb + c, N - 1);

    f32x4 acc[NT];
#pragma unroll
    for (int t = 0; t < NT; ++t) acc[t] = (f32x4){0.f, 0.f, 0.f, 0.f};

    for (int s = 0; s < NREL + 1; ++s) {
        const ushort* Aseg = (s < NREL) ? (agg + (size_t)s * N * D_IN) : feat;
        // stage swizzled B segment (NCOLS x 128 bf16) linearly into LDS
        {
            const uint4* srcw = (const uint4*)(Wt + (size_t)s * NCOLS * D_IN);
            uint4* dstw = (uint4*)Bt;
#pragma unroll
            for (int i = 0; i < (NCOLS * D_IN) / (8 * 256); ++i)
                dstw[tid + i * 256] = srcw[tid + i * 256];
        }
        __syncthreads();
        const ushort* Abase = Aseg + (size_t)arow * D_IN + 8 * g;
#pragma unroll
        for (int kt = 0; kt < D_IN; kt += 32) {
            bf16x8 a = *(const bf16x8*)(Abase + kt);
#pragma unroll
            for (int t = 0; t < NT; ++t) {
                int n = t * 16 + c;
                int byteoff = n * 256 + ((kt * 2 + g * 16) ^ ((n & 7) << 4));
                bf16x8 b = *(const bf16x8*)((const char*)Bt + byteoff);
                acc[t] = __builtin_amdgcn_mfma_f32_16x16x32_bf16(a, b, acc[t], 0, 0, 0);
            }
        }
        __syncthreads();
    }

    // epilogue: D layout col=lane&15, row=(lane>>4)*4+reg
#pragma unroll
    for (int t = 0; t < NT; ++t) {
        float bv = bias[t * 16 + c];
#pragma unroll
        for (int r = 0; r < 4; ++r) {
            int orow = rb + 4 * g + r;
            if (orow < N) {
                float v = acc[t][r] + bv;
                if (RELU) v = fmaxf(v, 0.0f);
                if (OUTBF16)
                    ((ushort*)outp)[(size_t)orow * NCOLS + t * 16 + c] = cvbf(v);
                else
                    ((float*)outp)[(size_t)orow * NCOLS + t * 16 + c] = v;
            }
        }
    }
}

extern "C" void kernel_launch(void* const* d_in, const int* in_sizes, int n_in,
                              void* d_out, int out_size, void* d_ws, size_t ws_size,
                              hipStream_t stream) {
    const float* x = (const float*)d_in[0];
    const int* ei = (const int*)d_in[1];
    const int* et = (const int*)d_in[2];
    const float* W1 = (const float*)d_in[3];
    const float* root1 = (const float*)d_in[4];
    const float* bias1 = (const float*)d_in[5];
    const float* W2 = (const float*)d_in[6];
    const float* root2 = (const float*)d_in[7];
    const float* bias2 = (const float*)d_in[8];
    float* out = (float*)d_out;

    const int N = in_sizes[0] / D_IN;  // 50000
    const int E = in_sizes[2];         // 800000
    const int* src = ei;
    const int* dst = ei + E;
    const int NSEG = NREL * N;            // 400000
    const int NB = (NSEG + 1023) / 1024;  // 391 (<=512 for scan_bsum)

    // workspace layout (all 16B-aligned)
    ushort* aggb = (ushort*)d_ws;                    // NSEG*128 bf16 = 102.4 MB
    ushort* xb = aggb + (size_t)NSEG * D_IN;         // N*128 bf16    = 12.8 MB
    ushort* hb = xb + (size_t)N * D_IN;              // N*128 bf16    = 12.8 MB
    ushort* wt1 = hb + (size_t)N * D_IN;             // 9*128*128     = 0.3 MB
    ushort* wt2 = wt1 + (size_t)(NREL + 1) * D_IN * D_IN;  // 9*64*128 = 0.15 MB
    int* off = (int*)(wt2 + (size_t)(NREL + 1) * 64 * D_IN);  // NSEG ints
    int* sids = off + NSEG;                          // E ints
    int* cnt = sids + E;                             // NSEG ints
    int* bsum = cnt + NSEG;                          // NB ints

    // ---- input conversions / weight transforms (independent) ----
    to_bf16_kernel<<<(N * D_IN / 4 + 255) / 256, 256, 0, stream>>>(x, xb, N * D_IN / 4);
    wt_transform_kernel<<<((NREL + 1) * D_IN * 128 + 255) / 256, 256, 0, stream>>>(
        W1, root1, wt1, 128);
    wt_transform_kernel<<<((NREL + 1) * D_IN * 64 + 255) / 256, 256, 0, stream>>>(
        W2, root2, wt2, 64);

    // ---- CSR build (edge set identical for both layers) ----
    hipMemsetAsync(cnt, 0, (size_t)NSEG * sizeof(int), stream);
    count_kernel<<<(E + 255) / 256, 256, 0, stream>>>(dst, et, cnt, E, N);
    scan_block_sum<<<NB, 256, 0, stream>>>(cnt, bsum, NSEG);
    scan_bsum<<<1, 512, 0, stream>>>(bsum, NB);
    scan_write<<<NB, 256, 0, stream>>>(cnt, bsum, off, NSEG);
    bucket_kernel<<<(E + 255) / 256, 256, 0, stream>>>(src, dst, et, off, sids, E, N);
    // off[] now holds END offsets per segment.

    const int aggBlocks = (int)(((size_t)NSEG * 16 + 255) / 256);
    const int gemmBlocks = (N + 63) / 64;

    // ---- layer 1 ----
    aggregate_kernel<<<aggBlocks, 256, 0, stream>>>(xb, sids, off, aggb, NSEG);
    mfma_gemm_kernel<128, true, true><<<gemmBlocks, 256, 0, stream>>>(
        xb, aggb, wt1, bias1, hb, N);

    // ---- layer 2 ----
    aggregate_kernel<<<aggBlocks, 256, 0, stream>>>(hb, sids, off, aggb, NSEG);
    mfma_gemm_kernel<64, false, false><<<gemmBlocks, 256, 0, stream>>>(
        hb, aggb, wt2, bias2, out, N);
}

// Round 13
// 251.593 us; speedup vs baseline: 1.4521x; 1.0980x over previous
//
#include <hip/hip_runtime.h>
#include <hip/hip_bf16.h>

// Two-layer RGCN (mean aggregation per relation) for MI355X.
// Round 13: r6 pipeline (best-measured skeleton). Changes vs r6:
//  - sids stored as ushort (src < 65536): halves bucket scatter churn and
//    agg sids traffic
//  - aggregate restored to r6 batched-shfl form (r12's direct-load version
//    regressed 49.7 -> 54 us)
// CSR relation-major (seg = et*N + dst). r6 = 262.4 us, r12 = 276.3 us.

#define D_IN 128
#define NREL 8

typedef short bf16x8 __attribute__((ext_vector_type(8)));
typedef float f32x4 __attribute__((ext_vector_type(4)));

__device__ __forceinline__ ushort cvbf(float f) {  // f32 -> bf16 RNE
    unsigned u = __float_as_uint(f);
    return (ushort)((u + 0x7FFFu + ((u >> 16) & 1u)) >> 16);
}
__device__ __forceinline__ float bflo(unsigned v) { return __uint_as_float(v << 16); }
__device__ __forceinline__ float bfhi(unsigned v) { return __uint_as_float(v & 0xFFFF0000u); }

// ---------------- f32 -> bf16 convert (4 elems/thread) ----------------
__global__ void to_bf16_kernel(const float* __restrict__ in,
                               ushort* __restrict__ out, int n4) {
    int i = blockIdx.x * blockDim.x + threadIdx.x;
    if (i >= n4) return;
    float4 v = ((const float4*)in)[i];
    ushort4 o;
    o.x = cvbf(v.x); o.y = cvbf(v.y); o.z = cvbf(v.z); o.w = cvbf(v.w);
    ((ushort4*)out)[i] = o;
}

// ---------------- weight pre-transform: bf16, transposed, XOR-swizzled ------
// Wt[s][n][k'] where byte-in-row = (k*2) ^ ((n&7)<<4). Segment s<NREL from W,
// s==NREL from root.
__global__ void wt_transform_kernel(const float* __restrict__ W,
                                    const float* __restrict__ root,
                                    ushort* __restrict__ Wt, int NCOLS) {
    int i = blockIdx.x * blockDim.x + threadIdx.x;
    int tot = (NREL + 1) * D_IN * NCOLS;
    if (i >= tot) return;
    int s = i / (D_IN * NCOLS);
    int r = i - s * D_IN * NCOLS;
    int k = r / NCOLS;
    int n = r - k * NCOLS;
    float v = (s < NREL) ? W[(size_t)s * D_IN * NCOLS + (size_t)k * NCOLS + n]
                         : root[(size_t)k * NCOLS + n];
    int byteoff = (k << 1) ^ ((n & 7) << 4);
    Wt[(size_t)s * NCOLS * D_IN + (size_t)n * D_IN + (byteoff >> 1)] = cvbf(v);
}

// ---------------- CSR build (seg = et*N + dst, relation-major) -------------
__global__ void count_kernel(const int* __restrict__ dst,
                             const int* __restrict__ et,
                             int* __restrict__ cnt, int E, int N) {
    int e = blockIdx.x * blockDim.x + threadIdx.x;
    if (e < E) atomicAdd(&cnt[et[e] * N + dst[e]], 1);
}

__global__ void scan_block_sum(const int* __restrict__ cnt,
                               int* __restrict__ bsum, int nseg) {
    __shared__ int s[256];
    int base = blockIdx.x * 1024 + threadIdx.x * 4;
    int v = 0;
#pragma unroll
    for (int i = 0; i < 4; ++i) {
        int idx = base + i;
        if (idx < nseg) v += cnt[idx];
    }
    s[threadIdx.x] = v;
    __syncthreads();
    for (int off = 128; off > 0; off >>= 1) {
        if (threadIdx.x < off) s[threadIdx.x] += s[threadIdx.x + off];
        __syncthreads();
    }
    if (threadIdx.x == 0) bsum[blockIdx.x] = s[0];
}

__global__ void scan_bsum(int* __restrict__ bsum, int nb) {
    __shared__ int s[512];
    int t = threadIdx.x;
    int my = (t < nb) ? bsum[t] : 0;
    s[t] = my;
    __syncthreads();
    for (int off = 1; off < 512; off <<= 1) {
        int v = (t >= off) ? s[t - off] : 0;
        __syncthreads();
        s[t] += v;
        __syncthreads();
    }
    if (t < nb) bsum[t] = s[t] - my;  // exclusive
}

__global__ void scan_write(const int* __restrict__ cnt,
                           const int* __restrict__ bsum,
                           int* __restrict__ off, int nseg) {
    __shared__ int s[256];
    int t = threadIdx.x;
    int base = blockIdx.x * 1024 + t * 4;
    int v[4];
    int sum = 0;
#pragma unroll
    for (int i = 0; i < 4; ++i) {
        int idx = base + i;
        v[i] = (idx < nseg) ? cnt[idx] : 0;
        sum += v[i];
    }
    s[t] = sum;
    __syncthreads();
    int my = sum;
    for (int o = 1; o < 256; o <<= 1) {
        int x = (t >= o) ? s[t - o] : 0;
        __syncthreads();
        s[t] += x;
        __syncthreads();
    }
    int pre = s[t] - my + bsum[blockIdx.x];
#pragma unroll
    for (int i = 0; i < 4; ++i) {
        int idx = base + i;
        if (idx < nseg) {
            off[idx] = pre;
            pre += v[i];
        }
    }
}

__global__ void bucket_kernel(const int* __restrict__ src,
                              const int* __restrict__ dst,
                              const int* __restrict__ et,
                              int* __restrict__ off,
                              ushort* __restrict__ sids, int E, int N) {
    int e = blockIdx.x * blockDim.x + threadIdx.x;
    if (e < E) {
        int seg = et[e] * N + dst[e];
        int pos = atomicAdd(&off[seg], 1);
        sids[pos] = (ushort)src[e];
    }
}

// -------- atomic-free segment mean (bf16 in/out): 16-lane group / segment ---
// 4 segments per wave; lane handles 16 B (8 bf16 channels) of the 256 B row.
// sids block-loaded 16-at-a-time and broadcast via shfl (amortizes latency).
__global__ __launch_bounds__(256) void aggregate_kernel(
    const ushort* __restrict__ feat,    // [N][128] bf16
    const ushort* __restrict__ sids,    // [E] src ids grouped by segment
    const int* __restrict__ endoff,     // [nseg] end offsets
    ushort* __restrict__ agg,           // [nseg][128] bf16 means
    int nseg) {
    int gid = blockIdx.x * blockDim.x + threadIdx.x;
    int s = gid >> 4;           // one segment per 16 threads
    int l = gid & 15;           // lane within group
    if (s >= nseg) return;
    int gbase = threadIdx.x & 48;  // group's base lane within the wave

    int end = endoff[s];
    int start = (s == 0) ? 0 : endoff[s - 1];
    int deg = end - start;

    float a0 = 0.f, a1 = 0.f, a2 = 0.f, a3 = 0.f;
    float a4 = 0.f, a5 = 0.f, a6 = 0.f, a7 = 0.f;
    for (int base = start; base < end; base += 16) {
        int m = min(16, end - base);
        int sid = (l < m) ? (int)sids[base + l] : 0;
#pragma unroll 2
        for (int j = 0; j < m; ++j) {
            int id = __shfl(sid, gbase + j);
            uint4 v = ((const uint4*)(feat + (size_t)id * D_IN))[l];
            a0 += bflo(v.x); a1 += bfhi(v.x);
            a2 += bflo(v.y); a3 += bfhi(v.y);
            a4 += bflo(v.z); a5 += bfhi(v.z);
            a6 += bflo(v.w); a7 += bfhi(v.w);
        }
    }
    float inv = (deg > 0) ? 1.0f / (float)deg : 0.0f;
    uint4 o;
    o.x = (unsigned)cvbf(a0 * inv) | ((unsigned)cvbf(a1 * inv) << 16);
    o.y = (unsigned)cvbf(a2 * inv) | ((unsigned)cvbf(a3 * inv) << 16);
    o.z = (unsigned)cvbf(a4 * inv) | ((unsigned)cvbf(a5 * inv) << 16);
    o.w = (unsigned)cvbf(a6 * inv) | ((unsigned)cvbf(a7 * inv) << 16);
    ((uint4*)(agg + (size_t)s * D_IN))[l] = o;
}

// ---------------- MFMA fused RGCN GEMM (round-6 exact) ----------------
// out[n][j] = bias[j] + feat[n]@root[:,j] + sum_r agg[r*N+n] @ W[r][:,j]
template <int NCOLS, bool RELU, bool OUTBF16>
__global__ __launch_bounds__(256) void mfma_gemm_kernel(
    const ushort* __restrict__ feat,  // [N][128] bf16
    const ushort* __restrict__ agg,   // [R][N][128] bf16
    const ushort* __restrict__ Wt,    // [R+1][NCOLS][128] bf16 swizzled
    const float* __restrict__ bias,   // [NCOLS]
    void* __restrict__ outp,          // [N][NCOLS] bf16 or f32
    int N) {
    constexpr int NT = NCOLS / 16;  // 16x16 col-tiles per wave
    __shared__ ushort Bt[NCOLS * D_IN];

    const int tid = threadIdx.x;
    const int wave = tid >> 6;
    const int lane = tid & 63;
    const int c = lane & 15;   // A-row / D-col / B-col within tile
    const int g = lane >> 4;   // k-group
    const int rb = blockIdx.x * 64 + wave * 16;
    const int arow = min(rb + c, N - 1);

    f32x4 acc[NT];
#pragma unroll
    for (int t = 0; t < NT; ++t) acc[t] = (f32x4){0.f, 0.f, 0.f, 0.f};

    for (int s = 0; s < NREL + 1; ++s) {
        const ushort* Aseg = (s < NREL) ? (agg + (size_t)s * N * D_IN) : feat;
        // stage swizzled B segment (NCOLS x 128 bf16) linearly into LDS
        {
            const uint4* srcw = (const uint4*)(Wt + (size_t)s * NCOLS * D_IN);
            uint4* dstw = (uint4*)Bt;
#pragma unroll
            for (int i = 0; i < (NCOLS * D_IN) / (8 * 256); ++i)
                dstw[tid + i * 256] = srcw[tid + i * 256];
        }
        __syncthreads();
        const ushort* Abase = Aseg + (size_t)arow * D_IN + 8 * g;
#pragma unroll
        for (int kt = 0; kt < D_IN; kt += 32) {
            bf16x8 a = *(const bf16x8*)(Abase + kt);
#pragma unroll
            for (int t = 0; t < NT; ++t) {
                int n = t * 16 + c;
                int byteoff = n * 256 + ((kt * 2 + g * 16) ^ ((n & 7) << 4));
                bf16x8 b = *(const bf16x8*)((const char*)Bt + byteoff);
                acc[t] = __builtin_amdgcn_mfma_f32_16x16x32_bf16(a, b, acc[t], 0, 0, 0);
            }
        }
        __syncthreads();
    }

    // epilogue: D layout col=lane&15, row=(lane>>4)*4+reg
#pragma unroll
    for (int t = 0; t < NT; ++t) {
        float bv = bias[t * 16 + c];
#pragma unroll
        for (int r = 0; r < 4; ++r) {
            int orow = rb + 4 * g + r;
            if (orow < N) {
                float v = acc[t][r] + bv;
                if (RELU) v = fmaxf(v, 0.0f);
                if (OUTBF16)
                    ((ushort*)outp)[(size_t)orow * NCOLS + t * 16 + c] = cvbf(v);
                else
                    ((float*)outp)[(size_t)orow * NCOLS + t * 16 + c] = v;
            }
        }
    }
}

extern "C" void kernel_launch(void* const* d_in, const int* in_sizes, int n_in,
                              void* d_out, int out_size, void* d_ws, size_t ws_size,
                              hipStream_t stream) {
    const float* x = (const float*)d_in[0];
    const int* ei = (const int*)d_in[1];
    const int* et = (const int*)d_in[2];
    const float* W1 = (const float*)d_in[3];
    const float* root1 = (const float*)d_in[4];
    const float* bias1 = (const float*)d_in[5];
    const float* W2 = (const float*)d_in[6];
    const float* root2 = (const float*)d_in[7];
    const float* bias2 = (const float*)d_in[8];
    float* out = (float*)d_out;

    const int N = in_sizes[0] / D_IN;  // 50000
    const int E = in_sizes[2];         // 800000
    const int* src = ei;
    const int* dst = ei + E;
    const int NSEG = NREL * N;            // 400000
    const int NB = (NSEG + 1023) / 1024;  // 391 (<=512 for scan_bsum)

    // workspace layout (all 16B-aligned)
    ushort* aggb = (ushort*)d_ws;                    // NSEG*128 bf16 = 102.4 MB
    ushort* xb = aggb + (size_t)NSEG * D_IN;         // N*128 bf16    = 12.8 MB
    ushort* hb = xb + (size_t)N * D_IN;              // N*128 bf16    = 12.8 MB
    ushort* wt1 = hb + (size_t)N * D_IN;             // 9*128*128     = 0.3 MB
    ushort* wt2 = wt1 + (size_t)(NREL + 1) * D_IN * D_IN;  // 9*64*128 = 0.15 MB
    ushort* sids = wt2 + (size_t)(NREL + 1) * 64 * D_IN;   // E ushorts = 1.6 MB
    int* off = (int*)(sids + E);                     // NSEG ints
    int* cnt = off + NSEG;                           // NSEG ints
    int* bsum = cnt + NSEG;                          // NB ints

    // ---- input conversions / weight transforms (independent) ----
    to_bf16_kernel<<<(N * D_IN / 4 + 255) / 256, 256, 0, stream>>>(x, xb, N * D_IN / 4);
    wt_transform_kernel<<<((NREL + 1) * D_IN * 128 + 255) / 256, 256, 0, stream>>>(
        W1, root1, wt1, 128);
    wt_transform_kernel<<<((NREL + 1) * D_IN * 64 + 255) / 256, 256, 0, stream>>>(
        W2, root2, wt2, 64);

    // ---- CSR build (edge set identical for both layers) ----
    hipMemsetAsync(cnt, 0, (size_t)NSEG * sizeof(int), stream);
    count_kernel<<<(E + 255) / 256, 256, 0, stream>>>(dst, et, cnt, E, N);
    scan_block_sum<<<NB, 256, 0, stream>>>(cnt, bsum, NSEG);
    scan_bsum<<<1, 512, 0, stream>>>(bsum, NB);
    scan_write<<<NB, 256, 0, stream>>>(cnt, bsum, off, NSEG);
    bucket_kernel<<<(E + 255) / 256, 256, 0, stream>>>(src, dst, et, off, sids, E, N);
    // off[] now holds END offsets per segment.

    const int aggBlocks = (int)(((size_t)NSEG * 16 + 255) / 256);
    const int gemmBlocks = (N + 63) / 64;

    // ---- layer 1 ----
    aggregate_kernel<<<aggBlocks, 256, 0, stream>>>(xb, sids, off, aggb, NSEG);
    mfma_gemm_kernel<128, true, true><<<gemmBlocks, 256, 0, stream>>>(
        xb, aggb, wt1, bias1, hb, N);

    // ---- layer 2 ----
    aggregate_kernel<<<aggBlocks, 256, 0, stream>>>(hb, sids, off, aggb, NSEG);
    mfma_gemm_kernel<64, false, false><<<gemmBlocks, 256, 0, stream>>>(
        hb, aggb, wt2, bias2, out, N);
}